// Round 5
// baseline (838.581 us; speedup 1.0000x reference)
//
#include <hip/hip_runtime.h>

// EstraNetBlock: pre-norm linear attention (fourier feature kernel) + FFN.
// B=4, L=4096, D=1024, H=16, Dh=64, M=128 (2M=256), D_INNER=4096.
//
// R5: gemm256 K-loop = 2-deep full-tile counted pipeline: all 8 gload_lds for
// tile kt+1 issued at top of tile kt (into the buffer freed at kt-1's end),
// single s_waitcnt vmcnt(8) per K-tile (cover = one full K-tile of compute),
// 2 barriers/K-tile, compiler-scheduled ds_read/MFMA inside the tile.
//
// ws layout (MB):
//   arena 0..128 (reused as H[16384][4096] bf16 for FFN):
//     0  WQPT bf16[2048][1024]   4  WKPT bf16[2048][1024]
//     8  WVT bf16[1024][1024]   10  WOT bf16[1024][1024]
//     12 BQP f32[2048], BKP f32[2048]
//     16 VTg bf16[64][64][4096] (-> ATTN)   48 PH bf16[8192][2048]
//     80 PART f32[16][32][64][256]          112 KVacc f32[64][16384]
//     116 KVT bf16[64][16384]
//   128 X2 bf16[16384][1024] (-> X2B)
//   160 W1T bf16[4096][1024]   168 W2T bf16[1024][4096]   (total 176MB)

#define RS128 0.08838834764831845f

typedef short bf16x8 __attribute__((ext_vector_type(8)));
typedef float f32x4 __attribute__((ext_vector_type(4)));

__device__ __forceinline__ unsigned short f2bf(float f) {
  unsigned int u = __float_as_uint(f);
  u += 0x7fffu + ((u >> 16) & 1u);
  return (unsigned short)(u >> 16);
}
__device__ __forceinline__ float bf2f(unsigned short h) {
  return __uint_as_float(((unsigned int)h) << 16);
}
__device__ __forceinline__ unsigned int pack2f(float a, float b) {
  return (unsigned int)f2bf(a) | ((unsigned int)f2bf(b) << 16);
}
__device__ __forceinline__ void gload_lds16(const void* g, void* l) {
  __builtin_amdgcn_global_load_lds(
      (const __attribute__((address_space(1))) void*)g,
      (__attribute__((address_space(3))) void*)l, 16, 0, 0);
}
__device__ __forceinline__ void barrier_pin() {
  __builtin_amdgcn_sched_barrier(0);
  __builtin_amdgcn_s_barrier();
  __builtin_amdgcn_sched_barrier(0);
}
#define WAIT_VM(N) { asm volatile("s_waitcnt vmcnt(" #N ")" ::: "memory"); __builtin_amdgcn_sched_barrier(0); }

// ---------------- 256x256 8-wave GEMM: C = A @ Bt^T + bias (+res) -----------
// A[M][K], Bt[N][K] bf16; 512 threads = 8 waves (2M x 4N); per-wave 128x64 out.
// LDS 128KB: 2 bufs x (A 256x64 + B 256x64) bf16, XOR-swizzled byte^=(row&7)<<4.
// Pipeline: at top of tile kt, issue ALL 8 loads for kt+1, then vmcnt(8) --
// tile kt's loads were issued one full K-tile ago (max latency cover).
template <bool OBF16, bool RELU, bool RES>
__global__ __launch_bounds__(512, 2) void gemm256(
    const unsigned short* __restrict__ A, const unsigned short* __restrict__ Bt,
    void* Cv, const float* __restrict__ bias, const float* res,
    int M, int N, int K) {
  __shared__ __align__(16) char lds[131072];
  const int tid = threadIdx.x;
  const int lane = tid & 63, wid = tid >> 6;
  const int e = lane & 15, g = lane >> 4;
  const int wm = wid >> 2, wn = wid & 3;
  const int ntn = N >> 8;
  // bijective XCD swizzle (all grids are multiples of 8)
  const int nwg = (int)gridDim.x, cpx = nwg >> 3;
  const int swz = ((int)blockIdx.x & 7) * cpx + ((int)blockIdx.x >> 3);
  const int bm = swz / ntn, bn = swz % ntn;
  const long row0 = (long)bm << 8, col0 = (long)bn << 8;

  // staging: chunk c = 64 rows x 64 k (8KB), one gload_lds16 per thread.
  // LDS linear in row (stride 128B); global k-byte pre-swizzled by
  // ((row&7)<<4) so LDS reads use the same XOR (involution).
  const int srow = tid >> 3;
  const int skb = ((tid & 7) << 4) ^ ((srow & 7) << 4);
  const unsigned short* Abase = A + (row0 + srow) * (long)K + (skb >> 1);
  const unsigned short* Bbase = Bt + (col0 + srow) * (long)K + (skb >> 1);
  char* const ldsw = lds + (wid << 10);  // wave-uniform LDS dest base

  f32x4 acc[8][4] = {};
  const int nkt = K >> 6;
  const int rxA = (e & 7) << 4;  // read-side XOR (frag row &7 == e&7)

  // prologue: stage tile 0 into buf 0
#pragma unroll
  for (int c = 0; c < 4; ++c) {
    gload_lds16(Abase + (long)c * 64 * K, ldsw + c * 8192);
    gload_lds16(Bbase + (long)c * 64 * K, ldsw + 32768 + c * 8192);
  }

  for (int kt = 0; kt < nkt; ++kt) {
    char* Ac = lds + ((kt & 1) << 16);
    char* Bc = Ac + 32768;
    char* Anx = ldsw + (((kt & 1) ^ 1) << 16);
    // issue ALL next-tile loads first (buffer freed at kt-1's end barrier)
    if (kt + 1 < nkt) {
      const long kn = (long)(kt + 1) << 6;
#pragma unroll
      for (int c = 0; c < 4; ++c) {
        gload_lds16(Abase + (long)c * 64 * K + kn, Anx + c * 8192);
        gload_lds16(Bbase + (long)c * 64 * K + kn, Anx + 32768 + c * 8192);
      }
      WAIT_VM(8);  // tile kt's 8 loads (issued one tile ago) complete
    } else {
      WAIT_VM(0);
    }
    barrier_pin();  // all waves' staging of buf cur visible

    // B fragments for the whole K-tile
    bf16x8 bfr[4][2];
#pragma unroll
    for (int j = 0; j < 4; ++j) {
      const int r = wn * 64 + j * 16 + e;
#pragma unroll
      for (int kh = 0; kh < 2; ++kh)
        bfr[j][kh] = *(const bf16x8*)(Bc + r * 128 + ((g * 16 + kh * 64) ^ rxA));
    }
#pragma unroll
    for (int p = 0; p < 4; ++p) {
      bf16x8 af[2][2];
#pragma unroll
      for (int i = 0; i < 2; ++i) {
        const int r = wm * 128 + (2 * p + i) * 16 + e;
#pragma unroll
        for (int kh = 0; kh < 2; ++kh)
          af[i][kh] = *(const bf16x8*)(Ac + r * 128 + ((g * 16 + kh * 64) ^ rxA));
      }
      __builtin_amdgcn_s_setprio(1);
#pragma unroll
      for (int i = 0; i < 2; ++i)
#pragma unroll
        for (int j = 0; j < 4; ++j)
#pragma unroll
          for (int kh = 0; kh < 2; ++kh)
            acc[2 * p + i][j] = __builtin_amdgcn_mfma_f32_16x16x32_bf16(
                af[i][kh], bfr[j][kh], acc[2 * p + i][j], 0, 0, 0);
      __builtin_amdgcn_s_setprio(0);
    }
    barrier_pin();  // reads of buf cur done -> safe to overwrite next tile
  }

  // epilogue: C/D mapping col=lane&15, row=(lane>>4)*4+r
  const int r0 = wm * 128 + (g << 2);
  const int c0 = wn * 64 + e;
#pragma unroll
  for (int j = 0; j < 4; ++j) {
    const long gcol = col0 + c0 + (j << 4);
    const float bvv = bias[gcol];
#pragma unroll
    for (int mf = 0; mf < 8; ++mf) {
#pragma unroll
      for (int r = 0; r < 4; ++r) {
        const long grow = row0 + r0 + (mf << 4) + r;
        float v = acc[mf][j][r] + bvv;
        if (RES) v += res[grow * N + gcol];
        if (RELU) v = fmaxf(v, 0.f);
        if (OBF16) ((unsigned short*)Cv)[grow * N + gcol] = f2bf(v);
        else ((float*)Cv)[grow * N + gcol] = v;
      }
    }
  }
}

// -------- weight transpose + cast: W[K][N] f32 -> Wt[N][K] bf16 --------
__global__ __launch_bounds__(256) void wtrans(const float* __restrict__ W,
                                              unsigned short* __restrict__ Wt,
                                              int K, int N) {
  __shared__ float t[32][33];
  const int tx = threadIdx.x & 31, ty = threadIdx.x >> 5;
  const int n0 = blockIdx.x << 5, k0 = blockIdx.y << 5;
#pragma unroll
  for (int i = 0; i < 32; i += 8)
    t[ty + i][tx] = W[(long)(k0 + ty + i) * N + n0 + tx];
  __syncthreads();
#pragma unroll
  for (int i = 0; i < 32; i += 8)
    Wt[(long)(n0 + ty + i) * K + k0 + tx] = f2bf(t[tx][ty + i]);
}

// -------- WP prep: WPT[h*128+m][D] = 0.125 * sum_d w[D][h*64+d]*proj[d][m] ----
__global__ __launch_bounds__(256) void wp_prep(const float* __restrict__ w,
                                               const float* __restrict__ proj,
                                               unsigned short* __restrict__ WPT) {
  __shared__ float wkt[64 * 66];
  __shared__ float projL[64 * 128];
  const int tid = threadIdx.x;
  const int h = blockIdx.x, D0 = blockIdx.y << 6;
  {
    const int r = tid >> 2, dseg = (tid & 3) << 4;
    const float* src = w + (long)(D0 + r) * 1024 + h * 64 + dseg;
#pragma unroll
    for (int q = 0; q < 4; ++q) {
      float4 v = *(const float4*)(src + q * 4);
      wkt[(dseg + q * 4 + 0) * 66 + r] = v.x;
      wkt[(dseg + q * 4 + 1) * 66 + r] = v.y;
      wkt[(dseg + q * 4 + 2) * 66 + r] = v.z;
      wkt[(dseg + q * 4 + 3) * 66 + r] = v.w;
    }
#pragma unroll
    for (int q = 0; q < 8; ++q)
      *(float4*)(projL + tid * 32 + q * 4) = *(const float4*)(proj + tid * 32 + q * 4);
  }
  __syncthreads();
  const int r = tid & 63, mseg = (tid >> 6) << 5;
  float acc[32];
#pragma unroll
  for (int i = 0; i < 32; ++i) acc[i] = 0.f;
  for (int d = 0; d < 64; ++d) {
    const float wv = wkt[d * 66 + r];
    const float* pr = projL + d * 128 + mseg;
#pragma unroll
    for (int i = 0; i < 32; ++i) acc[i] += wv * pr[i];
  }
#pragma unroll
  for (int i = 0; i < 32; ++i)
    WPT[(long)(h * 128 + mseg + i) * 1024 + D0 + r] = f2bf(acc[i] * 0.125f);
}

// -------- BP prep --------
__global__ __launch_bounds__(256) void bp_prep(const float* __restrict__ b,
                                               const float* __restrict__ proj,
                                               float* __restrict__ BP) {
  const int hm = blockIdx.x * 256 + threadIdx.x;
  const int h = hm >> 7, m = hm & 127;
  float s = 0.f;
  for (int d = 0; d < 64; ++d) s += b[h * 64 + d] * proj[d * 128 + m];
  BP[hm] = s * 0.125f;
}

// -------- LayerNorm over 1024 cols, f32 in -> bf16 out --------
__global__ __launch_bounds__(256) void ln_kernel(const float* __restrict__ x,
                                                 const float* __restrict__ g,
                                                 const float* __restrict__ b,
                                                 unsigned short* __restrict__ out) {
  const int row = blockIdx.x, tid = threadIdx.x;
  const float* xr = x + (long)row * 1024;
  const float4 xv = *(const float4*)(xr + tid * 4);
  float s = xv.x + xv.y + xv.z + xv.w;
  float s2 = xv.x * xv.x + xv.y * xv.y + xv.z * xv.z + xv.w * xv.w;
#pragma unroll
  for (int off = 32; off > 0; off >>= 1) {
    s += __shfl_down(s, off);
    s2 += __shfl_down(s2, off);
  }
  __shared__ float ps[4], ps2[4];
  if ((tid & 63) == 0) { ps[tid >> 6] = s; ps2[tid >> 6] = s2; }
  __syncthreads();
  const float ts = ps[0] + ps[1] + ps[2] + ps[3];
  const float ts2 = ps2[0] + ps2[1] + ps2[2] + ps2[3];
  const float mu = ts * (1.f / 1024.f);
  const float rstd = rsqrtf(ts2 * (1.f / 1024.f) - mu * mu + 1e-5f);
  const float4 gv = *(const float4*)(g + tid * 4);
  const float4 bv = *(const float4*)(b + tid * 4);
  ushort4 o;
  o.x = f2bf((xv.x - mu) * rstd * gv.x + bv.x);
  o.y = f2bf((xv.y - mu) * rstd * gv.y + bv.y);
  o.z = f2bf((xv.z - mu) * rstd * gv.z + bv.z);
  o.w = f2bf((xv.w - mu) * rstd * gv.w + bv.w);
  *(ushort4*)(out + (long)row * 1024 + tid * 4) = o;
}

// -------- 128x128 GEMM with V-transpose epilogue (V path only) --------
__global__ __launch_bounds__(256, 2) void gemm_vt(
    const unsigned short* __restrict__ A, const unsigned short* __restrict__ Bt,
    void* Cv, const float* __restrict__ bias, int M, int N, int K) {
  __shared__ __align__(16) unsigned short sm[128 * 128];
  unsigned short* As = sm;
  unsigned short* Bs = sm + 128 * 64;
  const int tid = threadIdx.x;
  const int lane = tid & 63, wid = tid >> 6;
  const int ntn = N >> 7;
  const int bm = blockIdx.x / ntn, bn = blockIdx.x % ntn;
  const long row0 = (long)bm << 7, col0 = (long)bn << 7;
  const int wr = (wid >> 1) << 6, wc = (wid & 1) << 6;

  f32x4 acc[4][4] = {};
  const unsigned short* Ag = A + (row0 + (tid >> 3)) * (long)K + ((tid & 7) << 3);
  const unsigned short* Bg = Bt + (col0 + (tid >> 3)) * (long)K + ((tid & 7) << 3);
  char* AsB = (char*)As + (wid << 10);
  char* BsB = (char*)Bs + (wid << 10);

  for (int kt = 0; kt < K; kt += 64) {
#pragma unroll
    for (int c = 0; c < 4; ++c) {
      gload_lds16(Ag + kt + (long)c * 32 * K, AsB + (c << 12));
      gload_lds16(Bg + kt + (long)c * 32 * K, BsB + (c << 12));
    }
    __syncthreads();
#pragma unroll
    for (int kk = 0; kk < 2; ++kk) {
      const int krow = (kk << 5) + ((lane >> 4) << 3);
      bf16x8 af[4], bfr[4];
#pragma unroll
      for (int i = 0; i < 4; ++i)
        af[i] = *(const bf16x8*)(As + (wr + (i << 4) + (lane & 15)) * 64 + krow);
#pragma unroll
      for (int j = 0; j < 4; ++j)
        bfr[j] = *(const bf16x8*)(Bs + (wc + (j << 4) + (lane & 15)) * 64 + krow);
#pragma unroll
      for (int i = 0; i < 4; ++i)
#pragma unroll
        for (int j = 0; j < 4; ++j)
          acc[i][j] = __builtin_amdgcn_mfma_f32_16x16x32_bf16(af[i], bfr[j],
                                                              acc[i][j], 0, 0, 0);
    }
    __syncthreads();
  }

  const int r0 = wr + ((lane >> 4) << 2);
  const int c0l = wc + (lane & 15);
#pragma unroll
  for (int j = 0; j < 4; ++j) {
    const int cc = c0l + (j << 4);
    const float bvv = bias[col0 + cc];
#pragma unroll
    for (int i = 0; i < 4; ++i)
#pragma unroll
      for (int r = 0; r < 4; ++r) {
        const int ll = r0 + (i << 4) + r;
        sm[ll * 128 + (cc ^ ((ll & 7) << 1))] = f2bf(acc[i][j][r] + bvv);
      }
  }
  __syncthreads();
  const int c = tid & 127, lh = tid >> 7;
  const long gc = col0 + c;
  const int b = (int)(row0 >> 12);
  const int hh = (int)(gc >> 6), dd = (int)(gc & 63);
  const int lb = (int)(row0 & 4095) + lh * 64;
  char* basep = (char*)Cv + (((long)(b * 16 + hh) * 64 + dd) * 4096 + lb) * 2;
#pragma unroll
  for (int cc8 = 0; cc8 < 8; ++cc8) {
    unsigned short v[8];
#pragma unroll
    for (int k = 0; k < 8; ++k)
      v[k] = sm[(lh * 64 + cc8 * 8 + k) * 128 + (c ^ (k << 1))];
    uint4 o;
    o.x = (unsigned)v[0] | ((unsigned)v[1] << 16);
    o.y = (unsigned)v[2] | ((unsigned)v[3] << 16);
    o.z = (unsigned)v[4] | ((unsigned)v[5] << 16);
    o.w = (unsigned)v[6] | ((unsigned)v[7] << 16);
    *(uint4*)(basep + ((cc8 ^ (dd & 7)) << 4)) = o;
  }
}

// -------- kv kernel: PART[chunk][bhh][d][m] = sum_l vT[d][l]*kp[l][m] --------
__global__ __launch_bounds__(256, 2) void kv_kernel(
    const unsigned short* __restrict__ PH, const unsigned short* __restrict__ VTg,
    float* __restrict__ PART, int half) {
  __shared__ __align__(16) unsigned short Ps[64 * 128];
  __shared__ __align__(16) unsigned short Vs[64 * 64];
  __shared__ __align__(16) unsigned short KPT[256 * 64];
  const int tid = threadIdx.x;
  const int lane = tid & 63, wid = tid >> 6;
  const int bhh = blockIdx.x, chunk = blockIdx.y;
  const int b2 = bhh >> 4, h = bhh & 15;
  const int bh = (half * 2 + b2) * 16 + h;

  f32x4 acc[4][4] = {};
  const int e = lane & 15, g = lane >> 4;
  const int m = tid & 127, isin = tid >> 7;
  const int m2 = (isin << 7) + m, swm = m & 7;

  for (int ti = 0; ti < 4; ++ti) {
    const int l0 = chunk * 256 + ti * 64;
    __syncthreads();
#pragma unroll
    for (int c = 0; c < 4; ++c) {
      const int r = l0 + c * 16 + (tid >> 4);
      gload_lds16((const char*)PH + (long)(b2 * 4096 + r) * 4096 + h * 256 + (tid & 15) * 16,
                  (char*)Ps + c * 4096 + (wid << 10));
    }
#pragma unroll
    for (int c = 0; c < 2; ++c) {
      const int d = c * 32 + (tid >> 3);
      gload_lds16((const char*)VTg + ((long)(bh * 64 + d) * 4096 + l0) * 2 + (tid & 7) * 16,
                  (char*)Vs + c * 4096 + (wid << 10));
    }
    __syncthreads();
    {
      char* krow = (char*)KPT + m2 * 128;
#pragma unroll
      for (int g8 = 0; g8 < 8; ++g8) {
        unsigned pk[4];
#pragma unroll
        for (int k2 = 0; k2 < 4; ++k2) {
          const float p0 = bf2f(Ps[(g8 * 8 + k2 * 2) * 128 + m]);
          const float p1 = bf2f(Ps[(g8 * 8 + k2 * 2 + 1) * 128 + m]);
          const float v0 = (isin ? __sinf(p0) : __cosf(p0)) * RS128;
          const float v1 = (isin ? __sinf(p1) : __cosf(p1)) * RS128;
          pk[k2] = pack2f(v0, v1);
        }
        uint4 o; o.x = pk[0]; o.y = pk[1]; o.z = pk[2]; o.w = pk[3];
        *(uint4*)(krow + ((g8 ^ swm) << 4)) = o;
      }
    }
    __syncthreads();
#pragma unroll
    for (int kk = 0; kk < 2; ++kk) {
      const int ch = (kk << 2) + g;
      bf16x8 af[4], bfr[4];
#pragma unroll
      for (int i = 0; i < 4; ++i) {
        const int dr = (i << 4) + e;
        af[i] = *(const bf16x8*)((char*)Vs + dr * 128 + ((ch ^ (e & 7)) << 4));
      }
#pragma unroll
      for (int j = 0; j < 4; ++j) {
        const int mr = (wid << 6) + (j << 4) + e;
        bfr[j] = *(const bf16x8*)((char*)KPT + mr * 128 + ((ch ^ (e & 7)) << 4));
      }
#pragma unroll
      for (int i = 0; i < 4; ++i)
#pragma unroll
        for (int j = 0; j < 4; ++j)
          acc[i][j] = __builtin_amdgcn_mfma_f32_16x16x32_bf16(af[i], bfr[j],
                                                              acc[i][j], 0, 0, 0);
    }
  }
  float* slice = PART + ((long)chunk * 32 + bhh) * 16384;
#pragma unroll
  for (int i = 0; i < 4; ++i)
#pragma unroll
    for (int j = 0; j < 4; ++j)
#pragma unroll
      for (int r = 0; r < 4; ++r) {
        const int d = (i << 4) + (g << 2) + r;
        const int mc = (wid << 6) + (j << 4) + e;
        slice[d * 256 + mc] = acc[i][j][r];
      }
}

__global__ __launch_bounds__(256) void kv_reduce(const float* __restrict__ PART,
                                                 float* __restrict__ KVacc, int half) {
  const int bhh = blockIdx.x, seg = blockIdx.y;
  const long off = (long)bhh * 16384 + seg * 1024 + threadIdx.x * 4;
  float4 s = make_float4(0.f, 0.f, 0.f, 0.f);
#pragma unroll
  for (int c = 0; c < 16; ++c) {
    const float4 v = *(const float4*)(PART + ((long)c * 32) * 16384 + off);
    s.x += v.x; s.y += v.y; s.z += v.z; s.w += v.w;
  }
  *(float4*)(KVacc + (long)(half * 32) * 16384 + off) = s;
}

__global__ __launch_bounds__(256) void kvt_conv(const float* __restrict__ KVacc,
                                                unsigned short* __restrict__ KVT) {
  const int bh = blockIdx.x, tid = threadIdx.x;
  const int d = tid >> 2, mq = tid & 3;
  const float* src = KVacc + (long)bh * 16384 + d * 256 + mq * 64;
  char* dst = (char*)KVT + bh * 32768 + d * 512;
#pragma unroll
  for (int cc = 0; cc < 8; ++cc) {
    const float4 a = *(const float4*)(src + cc * 8);
    const float4 b = *(const float4*)(src + cc * 8 + 4);
    uint4 o;
    o.x = pack2f(a.x, a.y); o.y = pack2f(a.z, a.w);
    o.z = pack2f(b.x, b.y); o.w = pack2f(b.z, b.w);
    const int chunk = mq * 8 + cc;
    *(uint4*)(dst + ((chunk ^ (d & 7)) << 4)) = o;
  }
}

// -------- attn kernel: ATTN[l][h*64+d] = sum_m qp[l][m]*kvT[d][m] --------
__global__ __launch_bounds__(256, 2) void attn_kernel(
    const unsigned short* __restrict__ PH, const unsigned short* __restrict__ KVT,
    unsigned short* __restrict__ ATTN, int half) {
  __shared__ __align__(16) unsigned short QPs[64 * 256];
  __shared__ __align__(16) unsigned short KVs[64 * 256];
  const int tid = threadIdx.x;
  const int lane = tid & 63, wid = tid >> 6;
  const int bhh = blockIdx.x, chunk = blockIdx.y;
  const int b2 = bhh >> 4, h = bhh & 15;
  const int b = half * 2 + b2, bh = b * 16 + h;
  const int e = lane & 15, g = lane >> 4;

#pragma unroll
  for (int c = 0; c < 8; ++c)
    gload_lds16((const char*)KVT + bh * 32768 + c * 4096 + tid * 16,
                (char*)KVs + c * 4096 + (wid << 10));

  const int lrow = tid >> 2, ms = tid & 3, swl = lrow & 7;

  for (int ti = 0; ti < 4; ++ti) {
    const int l0 = chunk * 256 + ti * 64;
    const char* pg = (const char*)PH + (long)(b2 * 4096 + l0 + lrow) * 4096 + h * 256 + ms * 64;
    uint4 P[4];
#pragma unroll
    for (int q = 0; q < 4; ++q) P[q] = *(const uint4*)(pg + q * 16);
    uint4 CQ[4], SQ[4];
#pragma unroll
    for (int q = 0; q < 4; ++q) {
      const unsigned w[4] = {P[q].x, P[q].y, P[q].z, P[q].w};
      unsigned cw[4], sw[4];
#pragma unroll
      for (int k = 0; k < 4; ++k) {
        float c0, s0, c1, s1;
        __sincosf(bf2f((unsigned short)(w[k] & 0xffff)), &s0, &c0);
        __sincosf(bf2f((unsigned short)(w[k] >> 16)), &s1, &c1);
        cw[k] = pack2f(c0 * RS128, c1 * RS128);
        sw[k] = pack2f(s0 * RS128, s1 * RS128);
      }
      CQ[q].x = cw[0]; CQ[q].y = cw[1]; CQ[q].z = cw[2]; CQ[q].w = cw[3];
      SQ[q].x = sw[0]; SQ[q].y = sw[1]; SQ[q].z = sw[2]; SQ[q].w = sw[3];
    }
    __syncthreads();
    {
      char* qrow = (char*)QPs + lrow * 512;
#pragma unroll
      for (int q = 0; q < 4; ++q) {
        const int c = ms * 4 + q;
        *(uint4*)(qrow + ((c ^ swl) << 4)) = CQ[q];
        *(uint4*)(qrow + ((16 + (c ^ swl)) << 4)) = SQ[q];
      }
    }
    __syncthreads();
    f32x4 acc[4] = {};
    const int lr = (wid << 4) + e;
#pragma unroll
    for (int kk = 0; kk < 8; ++kk) {
      const int ch = (kk << 2) + g;
      const bf16x8 af = *(const bf16x8*)((char*)QPs + lr * 512 + ((ch ^ (e & 7)) << 4));
#pragma unroll
      for (int j = 0; j < 4; ++j) {
        const bf16x8 bfr = *(const bf16x8*)((char*)KVs + ((j << 4) + e) * 512 + ((ch ^ (e & 7)) << 4));
        acc[j] = __builtin_amdgcn_mfma_f32_16x16x32_bf16(af, bfr, acc[j], 0, 0, 0);
      }
    }
#pragma unroll
    for (int j = 0; j < 4; ++j)
#pragma unroll
      for (int r = 0; r < 4; ++r) {
        const int lo = (wid << 4) + (g << 2) + r;
        ATTN[(long)(b * 4096 + l0 + lo) * 1024 + h * 64 + (j << 4) + e] = f2bf(acc[j][r]);
      }
  }
}

extern "C" void kernel_launch(void* const* d_in, const int* in_sizes, int n_in,
                              void* d_out, int out_size, void* d_ws, size_t ws_size,
                              hipStream_t stream) {
  (void)in_sizes; (void)n_in; (void)out_size; (void)ws_size;
  const float* x    = (const float*)d_in[0];
  const float* proj = (const float*)d_in[1];
  const float* wq = (const float*)d_in[2];
  const float* bq = (const float*)d_in[3];
  const float* wk = (const float*)d_in[4];
  const float* bk = (const float*)d_in[5];
  const float* wv = (const float*)d_in[6];
  const float* bv = (const float*)d_in[7];
  const float* wo = (const float*)d_in[8];
  const float* bo = (const float*)d_in[9];
  const float* g1  = (const float*)d_in[10];
  const float* be1 = (const float*)d_in[11];
  const float* w1 = (const float*)d_in[12];
  const float* b1 = (const float*)d_in[13];
  const float* w2 = (const float*)d_in[14];
  const float* b2 = (const float*)d_in[15];
  const float* g2  = (const float*)d_in[16];
  const float* be2 = (const float*)d_in[17];
  float* out = (float*)d_out;

  char* ws = (char*)d_ws;
  const size_t MB = 1u << 20;
  unsigned short* WQPT = (unsigned short*)(ws + 0 * MB);
  unsigned short* WKPT = (unsigned short*)(ws + 4 * MB);
  unsigned short* WVT  = (unsigned short*)(ws + 8 * MB);
  unsigned short* WOT  = (unsigned short*)(ws + 10 * MB);
  float* BQP = (float*)(ws + 12 * MB);
  float* BKP = (float*)(ws + 12 * MB + 8192);
  unsigned short* VTg  = (unsigned short*)(ws + 16 * MB);   // -> ATTN
  unsigned short* PH   = (unsigned short*)(ws + 48 * MB);
  float* PART  = (float*)(ws + 80 * MB);
  float* KVacc = (float*)(ws + 112 * MB);
  unsigned short* KVT = (unsigned short*)(ws + 116 * MB);
  unsigned short* Hb  = (unsigned short*)(ws + 0 * MB);     // FFN hidden (128MB)
  unsigned short* X2  = (unsigned short*)(ws + 128 * MB);   // -> X2B
  unsigned short* W1T = (unsigned short*)(ws + 160 * MB);
  unsigned short* W2T = (unsigned short*)(ws + 168 * MB);
  unsigned short* ATTN = VTg;
  unsigned short* X2B  = X2;

  dim3 blk(256), blk5(512);

  // weights prep
  wtrans<<<dim3(32, 32), blk, 0, stream>>>(wv, WVT, 1024, 1024);
  wtrans<<<dim3(32, 32), blk, 0, stream>>>(wo, WOT, 1024, 1024);
  wtrans<<<dim3(128, 32), blk, 0, stream>>>(w1, W1T, 1024, 4096);
  wtrans<<<dim3(32, 128), blk, 0, stream>>>(w2, W2T, 4096, 1024);
  wp_prep<<<dim3(16, 16), blk, 0, stream>>>(wq, proj, WQPT);
  wp_prep<<<dim3(16, 16), blk, 0, stream>>>(wk, proj, WKPT);
  bp_prep<<<8, blk, 0, stream>>>(bq, proj, BQP);
  bp_prep<<<8, blk, 0, stream>>>(bk, proj, BKP);

  // LN1
  ln_kernel<<<16384, blk, 0, stream>>>(x, g1, be1, X2);

  // V gemm -> VTg (transposed + swizzled)
  gemm_vt<<<1024, blk, 0, stream>>>(X2, WVT, VTg, bv, 16384, 1024, 1024);

  // kv pipeline, two L-halves
  for (int half = 0; half < 2; ++half) {
    gemm256<true, false, false><<<256, blk5, 0, stream>>>(
        X2 + (long)half * 8192 * 1024, WKPT, PH, BKP, nullptr, 8192, 2048, 1024);
    kv_kernel<<<dim3(32, 16), blk, 0, stream>>>(PH, VTg, PART, half);
    kv_reduce<<<dim3(32, 16), blk, 0, stream>>>(PART, KVacc, half);
  }
  kvt_conv<<<64, blk, 0, stream>>>(KVacc, KVT);

  // attn pipeline, two L-halves
  for (int half = 0; half < 2; ++half) {
    gemm256<true, false, false><<<256, blk5, 0, stream>>>(
        X2 + (long)half * 8192 * 1024, WQPT, PH, BQP, nullptr, 8192, 2048, 1024);
    attn_kernel<<<dim3(32, 16), blk, 0, stream>>>(PH, KVT, ATTN, half);
  }

  // Wo + residual -> out (f32)
  gemm256<false, false, true><<<256, blk5, 0, stream>>>(
      ATTN, WOT, out, bo, x, 16384, 1024, 1024);

  // LN2
  ln_kernel<<<16384, blk, 0, stream>>>(out, g2, be2, X2B);

  // FFN (unchunked; H overwrites the arena, all dead by now)
  gemm256<true, true, false><<<1024, blk5, 0, stream>>>(
      X2B, W1T, Hb, b1, nullptr, 16384, 4096, 1024);
  gemm256<false, false, true><<<256, blk5, 0, stream>>>(
      Hb, W2T, out, b2, out, 16384, 1024, 4096);
}

// Round 6
// 804.731 us; speedup vs baseline: 1.0421x; 1.0421x over previous
//
#include <hip/hip_runtime.h>

// EstraNetBlock: pre-norm linear attention (fourier feature kernel) + FFN.
// B=4, L=4096, D=1024, H=16, Dh=64, M=128 (2M=256), D_INNER=4096.
//
// R6: gemm256 = 256x128 tile, 3-buffer LDS ring (144KB), 2 phases/K-tile,
// per-phase barrier pairs (wave role-split), counted vmcnt(6) only, tile kt+2
// staged during tile kt (>=2 K-tiles issue-to-wait cover). 8 waves = 4M x 2N.
//
// ws layout (MB): unchanged from R5.

#define RS128 0.08838834764831845f

typedef short bf16x8 __attribute__((ext_vector_type(8)));
typedef float f32x4 __attribute__((ext_vector_type(4)));

__device__ __forceinline__ unsigned short f2bf(float f) {
  unsigned int u = __float_as_uint(f);
  u += 0x7fffu + ((u >> 16) & 1u);
  return (unsigned short)(u >> 16);
}
__device__ __forceinline__ float bf2f(unsigned short h) {
  return __uint_as_float(((unsigned int)h) << 16);
}
__device__ __forceinline__ unsigned int pack2f(float a, float b) {
  return (unsigned int)f2bf(a) | ((unsigned int)f2bf(b) << 16);
}
__device__ __forceinline__ void gload_lds16(const void* g, void* l) {
  __builtin_amdgcn_global_load_lds(
      (const __attribute__((address_space(1))) void*)g,
      (__attribute__((address_space(3))) void*)l, 16, 0, 0);
}
__device__ __forceinline__ void barrier_pin() {
  __builtin_amdgcn_sched_barrier(0);
  __builtin_amdgcn_s_barrier();
  __builtin_amdgcn_sched_barrier(0);
}
#define WAIT_VM(N) { asm volatile("s_waitcnt vmcnt(" #N ")" ::: "memory"); __builtin_amdgcn_sched_barrier(0); }
#define WAIT_LGKM0() { asm volatile("s_waitcnt lgkmcnt(0)" ::: "memory"); __builtin_amdgcn_sched_barrier(0); }

// -------- 256x128-tile 8-wave GEMM: C = A @ Bt^T + bias (+res) --------------
// 512 thr = 8 waves (4M x 2N), per-wave 64x64 out (acc 4x4 frags).
// LDS: 3 ring bufs x 48KB (A 256x64 @+0, B 128x64 @+32768), rows 128B,
// XOR-swizzled byte^=(row&7)<<4 via pre-swizzled global source.
// Per K-tile: 2 phases, each {ds_read frags | stage 3 chunks of tile kt+2 |
// barrier | lgkm0 | setprio 16 MFMA | barrier}; vmcnt(6) at phase 1 validates
// tile kt+1 while kt+2's 6 loads stay in flight.
template <bool OBF16, bool RELU, bool RES>
__global__ __launch_bounds__(512, 2) void gemm256(
    const unsigned short* __restrict__ A, const unsigned short* __restrict__ Bt,
    void* Cv, const float* __restrict__ bias, const float* res,
    int M, int N, int K) {
  __shared__ __align__(16) char lds[147456];
  const int tid = threadIdx.x;
  const int lane = tid & 63, wid = tid >> 6;
  const int e = lane & 15, g = lane >> 4;
  const int wm = wid >> 1, wn = wid & 1;
  const int ntn = N >> 7;
  const int nwg = (int)gridDim.x, cpx = nwg >> 3;
  const int swz = ((int)blockIdx.x & 7) * cpx + ((int)blockIdx.x >> 3);
  const int bm = swz / ntn, bn = swz % ntn;
  const long row0 = (long)bm << 8, col0 = (long)bn << 7;

  // staging: chunk = 64 rows x 64 k (8KB); thread covers row tid>>3, 16B slot
  // (tid&7), global k-byte pre-XORed by ((row&7)<<4).
  const int srow = tid >> 3;
  const int skb = ((tid & 7) << 4) ^ ((srow & 7) << 4);
  const unsigned short* Abase = A + (row0 + srow) * (long)K + (skb >> 1);
  const unsigned short* Bbase = Bt + (col0 + srow) * (long)K + (skb >> 1);
  const int lof = wid << 10;

  f32x4 acc[4][4] = {};
  const int nkt = K >> 6;
  const int rx = (e & 7) << 4;

  char* bufA = lds;            // tile kt
  char* bufB = lds + 49152;    // tile kt+1
  char* bufC = lds + 98304;    // staging dest (tile kt+2)

  // prologue: tile 0 -> bufA, tile 1 -> bufB; wait tile 0 (tile 1 in flight)
#pragma unroll
  for (int c = 0; c < 4; ++c)
    gload_lds16(Abase + (long)c * 64 * K, bufA + lof + c * 8192);
#pragma unroll
  for (int c = 0; c < 2; ++c)
    gload_lds16(Bbase + (long)c * 64 * K, bufA + 32768 + lof + c * 8192);
#pragma unroll
  for (int c = 0; c < 4; ++c)
    gload_lds16(Abase + (long)c * 64 * K + 64, bufB + lof + c * 8192);
#pragma unroll
  for (int c = 0; c < 2; ++c)
    gload_lds16(Bbase + (long)c * 64 * K + 64, bufB + 32768 + lof + c * 8192);
  WAIT_VM(6);
  barrier_pin();

  for (int kt = 0; kt < nkt; ++kt) {
    char* Ac = bufA;
    char* Bc = bufA + 32768;
    const bool pf2 = (kt + 2 < nkt);
    const long kn2 = (long)(kt + 2) << 6;

    // ---------- phase 0: frags {af 0,1} + all bfr; stage A chunks 0-2 ------
    bf16x8 bfr[4][2];
#pragma unroll
    for (int j = 0; j < 4; ++j) {
      const int r = wn * 64 + j * 16 + e;
#pragma unroll
      for (int kh = 0; kh < 2; ++kh)
        bfr[j][kh] = *(const bf16x8*)(Bc + r * 128 + ((g * 16 + kh * 64) ^ rx));
    }
    bf16x8 af0[2][2];
#pragma unroll
    for (int i = 0; i < 2; ++i) {
      const int r = wm * 64 + i * 16 + e;
#pragma unroll
      for (int kh = 0; kh < 2; ++kh)
        af0[i][kh] = *(const bf16x8*)(Ac + r * 128 + ((g * 16 + kh * 64) ^ rx));
    }
    if (pf2) {
#pragma unroll
      for (int c = 0; c < 3; ++c)
        gload_lds16(Abase + (long)c * 64 * K + kn2, bufC + lof + c * 8192);
    }
    barrier_pin();
    WAIT_LGKM0();
    __builtin_amdgcn_s_setprio(1);
#pragma unroll
    for (int i = 0; i < 2; ++i)
#pragma unroll
      for (int j = 0; j < 4; ++j)
#pragma unroll
        for (int kh = 0; kh < 2; ++kh)
          acc[i][j] = __builtin_amdgcn_mfma_f32_16x16x32_bf16(
              af0[i][kh], bfr[j][kh], acc[i][j], 0, 0, 0);
    __builtin_amdgcn_s_setprio(0);
    barrier_pin();

    // ---------- phase 1: frags {af 2,3}; stage A chunk 3 + B chunks 0,1 ----
    bf16x8 af1[2][2];
#pragma unroll
    for (int i = 0; i < 2; ++i) {
      const int r = wm * 64 + (2 + i) * 16 + e;
#pragma unroll
      for (int kh = 0; kh < 2; ++kh)
        af1[i][kh] = *(const bf16x8*)(Ac + r * 128 + ((g * 16 + kh * 64) ^ rx));
    }
    if (pf2) {
      gload_lds16(Abase + (long)3 * 64 * K + kn2, bufC + lof + 3 * 8192);
      gload_lds16(Bbase + kn2, bufC + 32768 + lof);
      gload_lds16(Bbase + (long)64 * K + kn2, bufC + 32768 + lof + 8192);
      WAIT_VM(6);            // tile kt+1 resident; kt+2's 6 stay in flight
    } else if (kt + 1 < nkt) {
      WAIT_VM(0);            // tail
    }
    barrier_pin();
    WAIT_LGKM0();
    __builtin_amdgcn_s_setprio(1);
#pragma unroll
    for (int i = 0; i < 2; ++i)
#pragma unroll
      for (int j = 0; j < 4; ++j)
#pragma unroll
        for (int kh = 0; kh < 2; ++kh)
          acc[2 + i][j] = __builtin_amdgcn_mfma_f32_16x16x32_bf16(
              af1[i][kh], bfr[j][kh], acc[2 + i][j], 0, 0, 0);
    __builtin_amdgcn_s_setprio(0);
    barrier_pin();

    // rotate ring
    char* t = bufA; bufA = bufB; bufB = bufC; bufC = t;
  }

  // epilogue: C/D mapping col=lane&15, row=(lane>>4)*4+r
  const int r0 = wm * 64 + (g << 2);
  const int c0 = wn * 64 + e;
#pragma unroll
  for (int j = 0; j < 4; ++j) {
    const long gcol = col0 + c0 + (j << 4);
    const float bvv = bias[gcol];
#pragma unroll
    for (int mf = 0; mf < 4; ++mf) {
#pragma unroll
      for (int r = 0; r < 4; ++r) {
        const long grow = row0 + r0 + (mf << 4) + r;
        float v = acc[mf][j][r] + bvv;
        if (RES) v += res[grow * N + gcol];
        if (RELU) v = fmaxf(v, 0.f);
        if (OBF16) ((unsigned short*)Cv)[grow * N + gcol] = f2bf(v);
        else ((float*)Cv)[grow * N + gcol] = v;
      }
    }
  }
}

// -------- weight transpose + cast: W[K][N] f32 -> Wt[N][K] bf16 --------
__global__ __launch_bounds__(256) void wtrans(const float* __restrict__ W,
                                              unsigned short* __restrict__ Wt,
                                              int K, int N) {
  __shared__ float t[32][33];
  const int tx = threadIdx.x & 31, ty = threadIdx.x >> 5;
  const int n0 = blockIdx.x << 5, k0 = blockIdx.y << 5;
#pragma unroll
  for (int i = 0; i < 32; i += 8)
    t[ty + i][tx] = W[(long)(k0 + ty + i) * N + n0 + tx];
  __syncthreads();
#pragma unroll
  for (int i = 0; i < 32; i += 8)
    Wt[(long)(n0 + ty + i) * K + k0 + tx] = f2bf(t[tx][ty + i]);
}

// -------- WP prep: WPT[h*128+m][D] = 0.125 * sum_d w[D][h*64+d]*proj[d][m] ----
__global__ __launch_bounds__(256) void wp_prep(const float* __restrict__ w,
                                               const float* __restrict__ proj,
                                               unsigned short* __restrict__ WPT) {
  __shared__ float wkt[64 * 66];
  __shared__ float projL[64 * 128];
  const int tid = threadIdx.x;
  const int h = blockIdx.x, D0 = blockIdx.y << 6;
  {
    const int r = tid >> 2, dseg = (tid & 3) << 4;
    const float* src = w + (long)(D0 + r) * 1024 + h * 64 + dseg;
#pragma unroll
    for (int q = 0; q < 4; ++q) {
      float4 v = *(const float4*)(src + q * 4);
      wkt[(dseg + q * 4 + 0) * 66 + r] = v.x;
      wkt[(dseg + q * 4 + 1) * 66 + r] = v.y;
      wkt[(dseg + q * 4 + 2) * 66 + r] = v.z;
      wkt[(dseg + q * 4 + 3) * 66 + r] = v.w;
    }
#pragma unroll
    for (int q = 0; q < 8; ++q)
      *(float4*)(projL + tid * 32 + q * 4) = *(const float4*)(proj + tid * 32 + q * 4);
  }
  __syncthreads();
  const int r = tid & 63, mseg = (tid >> 6) << 5;
  float acc[32];
#pragma unroll
  for (int i = 0; i < 32; ++i) acc[i] = 0.f;
  for (int d = 0; d < 64; ++d) {
    const float wv = wkt[d * 66 + r];
    const float* pr = projL + d * 128 + mseg;
#pragma unroll
    for (int i = 0; i < 32; ++i) acc[i] += wv * pr[i];
  }
#pragma unroll
  for (int i = 0; i < 32; ++i)
    WPT[(long)(h * 128 + mseg + i) * 1024 + D0 + r] = f2bf(acc[i] * 0.125f);
}

// -------- BP prep --------
__global__ __launch_bounds__(256) void bp_prep(const float* __restrict__ b,
                                               const float* __restrict__ proj,
                                               float* __restrict__ BP) {
  const int hm = blockIdx.x * 256 + threadIdx.x;
  const int h = hm >> 7, m = hm & 127;
  float s = 0.f;
  for (int d = 0; d < 64; ++d) s += b[h * 64 + d] * proj[d * 128 + m];
  BP[hm] = s * 0.125f;
}

// -------- LayerNorm over 1024 cols, f32 in -> bf16 out --------
__global__ __launch_bounds__(256) void ln_kernel(const float* __restrict__ x,
                                                 const float* __restrict__ g,
                                                 const float* __restrict__ b,
                                                 unsigned short* __restrict__ out) {
  const int row = blockIdx.x, tid = threadIdx.x;
  const float* xr = x + (long)row * 1024;
  const float4 xv = *(const float4*)(xr + tid * 4);
  float s = xv.x + xv.y + xv.z + xv.w;
  float s2 = xv.x * xv.x + xv.y * xv.y + xv.z * xv.z + xv.w * xv.w;
#pragma unroll
  for (int off = 32; off > 0; off >>= 1) {
    s += __shfl_down(s, off);
    s2 += __shfl_down(s2, off);
  }
  __shared__ float ps[4], ps2[4];
  if ((tid & 63) == 0) { ps[tid >> 6] = s; ps2[tid >> 6] = s2; }
  __syncthreads();
  const float ts = ps[0] + ps[1] + ps[2] + ps[3];
  const float ts2 = ps2[0] + ps2[1] + ps2[2] + ps2[3];
  const float mu = ts * (1.f / 1024.f);
  const float rstd = rsqrtf(ts2 * (1.f / 1024.f) - mu * mu + 1e-5f);
  const float4 gv = *(const float4*)(g + tid * 4);
  const float4 bv = *(const float4*)(b + tid * 4);
  ushort4 o;
  o.x = f2bf((xv.x - mu) * rstd * gv.x + bv.x);
  o.y = f2bf((xv.y - mu) * rstd * gv.y + bv.y);
  o.z = f2bf((xv.z - mu) * rstd * gv.z + bv.z);
  o.w = f2bf((xv.w - mu) * rstd * gv.w + bv.w);
  *(ushort4*)(out + (long)row * 1024 + tid * 4) = o;
}

// -------- 128x128 GEMM with V-transpose epilogue (V path only) --------
__global__ __launch_bounds__(256, 2) void gemm_vt(
    const unsigned short* __restrict__ A, const unsigned short* __restrict__ Bt,
    void* Cv, const float* __restrict__ bias, int M, int N, int K) {
  __shared__ __align__(16) unsigned short sm[128 * 128];
  unsigned short* As = sm;
  unsigned short* Bs = sm + 128 * 64;
  const int tid = threadIdx.x;
  const int lane = tid & 63, wid = tid >> 6;
  const int ntn = N >> 7;
  const int bm = blockIdx.x / ntn, bn = blockIdx.x % ntn;
  const long row0 = (long)bm << 7, col0 = (long)bn << 7;
  const int wr = (wid >> 1) << 6, wc = (wid & 1) << 6;

  f32x4 acc[4][4] = {};
  const unsigned short* Ag = A + (row0 + (tid >> 3)) * (long)K + ((tid & 7) << 3);
  const unsigned short* Bg = Bt + (col0 + (tid >> 3)) * (long)K + ((tid & 7) << 3);
  char* AsB = (char*)As + (wid << 10);
  char* BsB = (char*)Bs + (wid << 10);

  for (int kt = 0; kt < K; kt += 64) {
#pragma unroll
    for (int c = 0; c < 4; ++c) {
      gload_lds16(Ag + kt + (long)c * 32 * K, AsB + (c << 12));
      gload_lds16(Bg + kt + (long)c * 32 * K, BsB + (c << 12));
    }
    __syncthreads();
#pragma unroll
    for (int kk = 0; kk < 2; ++kk) {
      const int krow = (kk << 5) + ((lane >> 4) << 3);
      bf16x8 af[4], bfr[4];
#pragma unroll
      for (int i = 0; i < 4; ++i)
        af[i] = *(const bf16x8*)(As + (wr + (i << 4) + (lane & 15)) * 64 + krow);
#pragma unroll
      for (int j = 0; j < 4; ++j)
        bfr[j] = *(const bf16x8*)(Bs + (wc + (j << 4) + (lane & 15)) * 64 + krow);
#pragma unroll
      for (int i = 0; i < 4; ++i)
#pragma unroll
        for (int j = 0; j < 4; ++j)
          acc[i][j] = __builtin_amdgcn_mfma_f32_16x16x32_bf16(af[i], bfr[j],
                                                              acc[i][j], 0, 0, 0);
    }
    __syncthreads();
  }

  const int r0 = wr + ((lane >> 4) << 2);
  const int c0l = wc + (lane & 15);
#pragma unroll
  for (int j = 0; j < 4; ++j) {
    const int cc = c0l + (j << 4);
    const float bvv = bias[col0 + cc];
#pragma unroll
    for (int i = 0; i < 4; ++i)
#pragma unroll
      for (int r = 0; r < 4; ++r) {
        const int ll = r0 + (i << 4) + r;
        sm[ll * 128 + (cc ^ ((ll & 7) << 1))] = f2bf(acc[i][j][r] + bvv);
      }
  }
  __syncthreads();
  const int c = tid & 127, lh = tid >> 7;
  const long gc = col0 + c;
  const int b = (int)(row0 >> 12);
  const int hh = (int)(gc >> 6), dd = (int)(gc & 63);
  const int lb = (int)(row0 & 4095) + lh * 64;
  char* basep = (char*)Cv + (((long)(b * 16 + hh) * 64 + dd) * 4096 + lb) * 2;
#pragma unroll
  for (int cc8 = 0; cc8 < 8; ++cc8) {
    unsigned short v[8];
#pragma unroll
    for (int k = 0; k < 8; ++k)
      v[k] = sm[(lh * 64 + cc8 * 8 + k) * 128 + (c ^ (k << 1))];
    uint4 o;
    o.x = (unsigned)v[0] | ((unsigned)v[1] << 16);
    o.y = (unsigned)v[2] | ((unsigned)v[3] << 16);
    o.z = (unsigned)v[4] | ((unsigned)v[5] << 16);
    o.w = (unsigned)v[6] | ((unsigned)v[7] << 16);
    *(uint4*)(basep + ((cc8 ^ (dd & 7)) << 4)) = o;
  }
}

// -------- kv kernel: PART[chunk][bhh][d][m] = sum_l vT[d][l]*kp[l][m] --------
__global__ __launch_bounds__(256, 2) void kv_kernel(
    const unsigned short* __restrict__ PH, const unsigned short* __restrict__ VTg,
    float* __restrict__ PART, int half) {
  __shared__ __align__(16) unsigned short Ps[64 * 128];
  __shared__ __align__(16) unsigned short Vs[64 * 64];
  __shared__ __align__(16) unsigned short KPT[256 * 64];
  const int tid = threadIdx.x;
  const int lane = tid & 63, wid = tid >> 6;
  const int bhh = blockIdx.x, chunk = blockIdx.y;
  const int b2 = bhh >> 4, h = bhh & 15;
  const int bh = (half * 2 + b2) * 16 + h;

  f32x4 acc[4][4] = {};
  const int e = lane & 15, g = lane >> 4;
  const int m = tid & 127, isin = tid >> 7;
  const int m2 = (isin << 7) + m, swm = m & 7;

  for (int ti = 0; ti < 4; ++ti) {
    const int l0 = chunk * 256 + ti * 64;
    __syncthreads();
#pragma unroll
    for (int c = 0; c < 4; ++c) {
      const int r = l0 + c * 16 + (tid >> 4);
      gload_lds16((const char*)PH + (long)(b2 * 4096 + r) * 4096 + h * 256 + (tid & 15) * 16,
                  (char*)Ps + c * 4096 + (wid << 10));
    }
#pragma unroll
    for (int c = 0; c < 2; ++c) {
      const int d = c * 32 + (tid >> 3);
      gload_lds16((const char*)VTg + ((long)(bh * 64 + d) * 4096 + l0) * 2 + (tid & 7) * 16,
                  (char*)Vs + c * 4096 + (wid << 10));
    }
    __syncthreads();
    {
      char* krow = (char*)KPT + m2 * 128;
#pragma unroll
      for (int g8 = 0; g8 < 8; ++g8) {
        unsigned pk[4];
#pragma unroll
        for (int k2 = 0; k2 < 4; ++k2) {
          const float p0 = bf2f(Ps[(g8 * 8 + k2 * 2) * 128 + m]);
          const float p1 = bf2f(Ps[(g8 * 8 + k2 * 2 + 1) * 128 + m]);
          const float v0 = (isin ? __sinf(p0) : __cosf(p0)) * RS128;
          const float v1 = (isin ? __sinf(p1) : __cosf(p1)) * RS128;
          pk[k2] = pack2f(v0, v1);
        }
        uint4 o; o.x = pk[0]; o.y = pk[1]; o.z = pk[2]; o.w = pk[3];
        *(uint4*)(krow + ((g8 ^ swm) << 4)) = o;
      }
    }
    __syncthreads();
#pragma unroll
    for (int kk = 0; kk < 2; ++kk) {
      const int ch = (kk << 2) + g;
      bf16x8 af[4], bfr[4];
#pragma unroll
      for (int i = 0; i < 4; ++i) {
        const int dr = (i << 4) + e;
        af[i] = *(const bf16x8*)((char*)Vs + dr * 128 + ((ch ^ (e & 7)) << 4));
      }
#pragma unroll
      for (int j = 0; j < 4; ++j) {
        const int mr = (wid << 6) + (j << 4) + e;
        bfr[j] = *(const bf16x8*)((char*)KPT + mr * 128 + ((ch ^ (e & 7)) << 4));
      }
#pragma unroll
      for (int i = 0; i < 4; ++i)
#pragma unroll
        for (int j = 0; j < 4; ++j)
          acc[i][j] = __builtin_amdgcn_mfma_f32_16x16x32_bf16(af[i], bfr[j],
                                                              acc[i][j], 0, 0, 0);
    }
  }
  float* slice = PART + ((long)chunk * 32 + bhh) * 16384;
#pragma unroll
  for (int i = 0; i < 4; ++i)
#pragma unroll
    for (int j = 0; j < 4; ++j)
#pragma unroll
      for (int r = 0; r < 4; ++r) {
        const int d = (i << 4) + (g << 2) + r;
        const int mc = (wid << 6) + (j << 4) + e;
        slice[d * 256 + mc] = acc[i][j][r];
      }
}

__global__ __launch_bounds__(256) void kv_reduce(const float* __restrict__ PART,
                                                 float* __restrict__ KVacc, int half) {
  const int bhh = blockIdx.x, seg = blockIdx.y;
  const long off = (long)bhh * 16384 + seg * 1024 + threadIdx.x * 4;
  float4 s = make_float4(0.f, 0.f, 0.f, 0.f);
#pragma unroll
  for (int c = 0; c < 16; ++c) {
    const float4 v = *(const float4*)(PART + ((long)c * 32) * 16384 + off);
    s.x += v.x; s.y += v.y; s.z += v.z; s.w += v.w;
  }
  *(float4*)(KVacc + (long)(half * 32) * 16384 + off) = s;
}

__global__ __launch_bounds__(256) void kvt_conv(const float* __restrict__ KVacc,
                                                unsigned short* __restrict__ KVT) {
  const int bh = blockIdx.x, tid = threadIdx.x;
  const int d = tid >> 2, mq = tid & 3;
  const float* src = KVacc + (long)bh * 16384 + d * 256 + mq * 64;
  char* dst = (char*)KVT + bh * 32768 + d * 512;
#pragma unroll
  for (int cc = 0; cc < 8; ++cc) {
    const float4 a = *(const float4*)(src + cc * 8);
    const float4 b = *(const float4*)(src + cc * 8 + 4);
    uint4 o;
    o.x = pack2f(a.x, a.y); o.y = pack2f(a.z, a.w);
    o.z = pack2f(b.x, b.y); o.w = pack2f(b.z, b.w);
    const int chunk = mq * 8 + cc;
    *(uint4*)(dst + ((chunk ^ (d & 7)) << 4)) = o;
  }
}

// -------- attn kernel: ATTN[l][h*64+d] = sum_m qp[l][m]*kvT[d][m] --------
__global__ __launch_bounds__(256, 2) void attn_kernel(
    const unsigned short* __restrict__ PH, const unsigned short* __restrict__ KVT,
    unsigned short* __restrict__ ATTN, int half) {
  __shared__ __align__(16) unsigned short QPs[64 * 256];
  __shared__ __align__(16) unsigned short KVs[64 * 256];
  const int tid = threadIdx.x;
  const int lane = tid & 63, wid = tid >> 6;
  const int bhh = blockIdx.x, chunk = blockIdx.y;
  const int b2 = bhh >> 4, h = bhh & 15;
  const int b = half * 2 + b2, bh = b * 16 + h;
  const int e = lane & 15, g = lane >> 4;

#pragma unroll
  for (int c = 0; c < 8; ++c)
    gload_lds16((const char*)KVT + bh * 32768 + c * 4096 + tid * 16,
                (char*)KVs + c * 4096 + (wid << 10));

  const int lrow = tid >> 2, ms = tid & 3, swl = lrow & 7;

  for (int ti = 0; ti < 4; ++ti) {
    const int l0 = chunk * 256 + ti * 64;
    const char* pg = (const char*)PH + (long)(b2 * 4096 + l0 + lrow) * 4096 + h * 256 + ms * 64;
    uint4 P[4];
#pragma unroll
    for (int q = 0; q < 4; ++q) P[q] = *(const uint4*)(pg + q * 16);
    uint4 CQ[4], SQ[4];
#pragma unroll
    for (int q = 0; q < 4; ++q) {
      const unsigned w[4] = {P[q].x, P[q].y, P[q].z, P[q].w};
      unsigned cw[4], sw[4];
#pragma unroll
      for (int k = 0; k < 4; ++k) {
        float c0, s0, c1, s1;
        __sincosf(bf2f((unsigned short)(w[k] & 0xffff)), &s0, &c0);
        __sincosf(bf2f((unsigned short)(w[k] >> 16)), &s1, &c1);
        cw[k] = pack2f(c0 * RS128, c1 * RS128);
        sw[k] = pack2f(s0 * RS128, s1 * RS128);
      }
      CQ[q].x = cw[0]; CQ[q].y = cw[1]; CQ[q].z = cw[2]; CQ[q].w = cw[3];
      SQ[q].x = sw[0]; SQ[q].y = sw[1]; SQ[q].z = sw[2]; SQ[q].w = sw[3];
    }
    __syncthreads();
    {
      char* qrow = (char*)QPs + lrow * 512;
#pragma unroll
      for (int q = 0; q < 4; ++q) {
        const int c = ms * 4 + q;
        *(uint4*)(qrow + ((c ^ swl) << 4)) = CQ[q];
        *(uint4*)(qrow + ((16 + (c ^ swl)) << 4)) = SQ[q];
      }
    }
    __syncthreads();
    f32x4 acc[4] = {};
    const int lr = (wid << 4) + e;
#pragma unroll
    for (int kk = 0; kk < 8; ++kk) {
      const int ch = (kk << 2) + g;
      const bf16x8 af = *(const bf16x8*)((char*)QPs + lr * 512 + ((ch ^ (e & 7)) << 4));
#pragma unroll
      for (int j = 0; j < 4; ++j) {
        const bf16x8 bfr = *(const bf16x8*)((char*)KVs + ((j << 4) + e) * 512 + ((ch ^ (e & 7)) << 4));
        acc[j] = __builtin_amdgcn_mfma_f32_16x16x32_bf16(af, bfr, acc[j], 0, 0, 0);
      }
    }
#pragma unroll
    for (int j = 0; j < 4; ++j)
#pragma unroll
      for (int r = 0; r < 4; ++r) {
        const int lo = (wid << 4) + (g << 2) + r;
        ATTN[(long)(b * 4096 + l0 + lo) * 1024 + h * 64 + (j << 4) + e] = f2bf(acc[j][r]);
      }
  }
}

extern "C" void kernel_launch(void* const* d_in, const int* in_sizes, int n_in,
                              void* d_out, int out_size, void* d_ws, size_t ws_size,
                              hipStream_t stream) {
  (void)in_sizes; (void)n_in; (void)out_size; (void)ws_size;
  const float* x    = (const float*)d_in[0];
  const float* proj = (const float*)d_in[1];
  const float* wq = (const float*)d_in[2];
  const float* bq = (const float*)d_in[3];
  const float* wk = (const float*)d_in[4];
  const float* bk = (const float*)d_in[5];
  const float* wv = (const float*)d_in[6];
  const float* bv = (const float*)d_in[7];
  const float* wo = (const float*)d_in[8];
  const float* bo = (const float*)d_in[9];
  const float* g1  = (const float*)d_in[10];
  const float* be1 = (const float*)d_in[11];
  const float* w1 = (const float*)d_in[12];
  const float* b1 = (const float*)d_in[13];
  const float* w2 = (const float*)d_in[14];
  const float* b2 = (const float*)d_in[15];
  const float* g2  = (const float*)d_in[16];
  const float* be2 = (const float*)d_in[17];
  float* out = (float*)d_out;

  char* ws = (char*)d_ws;
  const size_t MB = 1u << 20;
  unsigned short* WQPT = (unsigned short*)(ws + 0 * MB);
  unsigned short* WKPT = (unsigned short*)(ws + 4 * MB);
  unsigned short* WVT  = (unsigned short*)(ws + 8 * MB);
  unsigned short* WOT  = (unsigned short*)(ws + 10 * MB);
  float* BQP = (float*)(ws + 12 * MB);
  float* BKP = (float*)(ws + 12 * MB + 8192);
  unsigned short* VTg  = (unsigned short*)(ws + 16 * MB);   // -> ATTN
  unsigned short* PH   = (unsigned short*)(ws + 48 * MB);
  float* PART  = (float*)(ws + 80 * MB);
  float* KVacc = (float*)(ws + 112 * MB);
  unsigned short* KVT = (unsigned short*)(ws + 116 * MB);
  unsigned short* Hb  = (unsigned short*)(ws + 0 * MB);     // FFN hidden (128MB)
  unsigned short* X2  = (unsigned short*)(ws + 128 * MB);   // -> X2B
  unsigned short* W1T = (unsigned short*)(ws + 160 * MB);
  unsigned short* W2T = (unsigned short*)(ws + 168 * MB);
  unsigned short* ATTN = VTg;
  unsigned short* X2B  = X2;

  dim3 blk(256), blk5(512);

  // weights prep
  wtrans<<<dim3(32, 32), blk, 0, stream>>>(wv, WVT, 1024, 1024);
  wtrans<<<dim3(32, 32), blk, 0, stream>>>(wo, WOT, 1024, 1024);
  wtrans<<<dim3(128, 32), blk, 0, stream>>>(w1, W1T, 1024, 4096);
  wtrans<<<dim3(32, 128), blk, 0, stream>>>(w2, W2T, 4096, 1024);
  wp_prep<<<dim3(16, 16), blk, 0, stream>>>(wq, proj, WQPT);
  wp_prep<<<dim3(16, 16), blk, 0, stream>>>(wk, proj, WKPT);
  bp_prep<<<8, blk, 0, stream>>>(bq, proj, BQP);
  bp_prep<<<8, blk, 0, stream>>>(bk, proj, BKP);

  // LN1
  ln_kernel<<<16384, blk, 0, stream>>>(x, g1, be1, X2);

  // V gemm -> VTg (transposed + swizzled)
  gemm_vt<<<1024, blk, 0, stream>>>(X2, WVT, VTg, bv, 16384, 1024, 1024);

  // kv pipeline, two L-halves  (grid = (M/256)*(N/128))
  for (int half = 0; half < 2; ++half) {
    gemm256<true, false, false><<<512, blk5, 0, stream>>>(
        X2 + (long)half * 8192 * 1024, WKPT, PH, BKP, nullptr, 8192, 2048, 1024);
    kv_kernel<<<dim3(32, 16), blk, 0, stream>>>(PH, VTg, PART, half);
    kv_reduce<<<dim3(32, 16), blk, 0, stream>>>(PART, KVacc, half);
  }
  kvt_conv<<<64, blk, 0, stream>>>(KVacc, KVT);

  // attn pipeline, two L-halves
  for (int half = 0; half < 2; ++half) {
    gemm256<true, false, false><<<512, blk5, 0, stream>>>(
        X2 + (long)half * 8192 * 1024, WQPT, PH, BQP, nullptr, 8192, 2048, 1024);
    attn_kernel<<<dim3(32, 16), blk, 0, stream>>>(PH, KVT, ATTN, half);
  }

  // Wo + residual -> out (f32)
  gemm256<false, false, true><<<512, blk5, 0, stream>>>(
      ATTN, WOT, out, bo, x, 16384, 1024, 1024);

  // LN2
  ln_kernel<<<16384, blk, 0, stream>>>(out, g2, be2, X2B);

  // FFN (unchunked)
  gemm256<true, true, false><<<2048, blk5, 0, stream>>>(
      X2B, W1T, Hb, b1, nullptr, 16384, 4096, 1024);
  gemm256<false, false, true><<<512, blk5, 0, stream>>>(
      Hb, W2T, out, b2, out, 16384, 1024, 4096);
}